// Round 9
// baseline (729.763 us; speedup 1.0000x reference)
//
#include <hip/hip_runtime.h>
#include <float.h>

// Tropical (max-plus) linear: y[b,o] = max_i (x[b,i] + W[o,i])
// B=512, I=1024, O=1024, fp32. No MFMA (max-plus semiring) -> fp32 VALU.
//
// Round-9 = round-8 codegen style + two knobs:
//  HARD RULES (r5/r7 demotion disasters): NO arrays of vector types for
//  register state. Scalar float arrays w/ constant indices; vector types only
//  as NAMED temporaries (float4 load temps, f32x2 pk-add temps).
//  Knob 1: v_pk_add_f32 via named f32x2 temps -> 1 VALU instr/MAC (was 1.5).
//     VALU floor 10.2 -> 6.8 us; LDS pipe (10.2 us) binding, 33% VALU slack
//     to absorb lgkmcnt stalls (r8's co-saturated pipes had zero slack).
//  Knob 2: 128-thread blocks (2 waves), tile 64x128, 1024 blocks = 4/CU:
//     4 independent barrier domains per CU -> one block's barrier drain
//     overlaps another's compute. Per-MAC LDS/VALU identical to r8.

#define B_DIM 512
#define I_DIM 1024
#define O_DIM 1024
#define BT 64            // b-tile per block
#define OT 128           // o-tile per block
#define KT 16            // k per staged chunk

typedef float f32x2 __attribute__((ext_vector_type(2)));

__device__ __forceinline__ void g2lds16(const float* g, float* l) {
    __builtin_amdgcn_global_load_lds(
        (const __attribute__((address_space(1))) void*)g,
        (__attribute__((address_space(3))) void*)l, 16, 0, 0);
}

template <int KB>   // k handled per block
__global__ __launch_bounds__(128, 2) void trop_main(
    const float* __restrict__ xT,   // [I_DIM][B_DIM]
    const float* __restrict__ wT,   // [I_DIM][O_DIM]
    float* __restrict__ part)       // [KSPLIT][B_DIM][O_DIM] (or y if z==1)
{
    constexpr int NCH = KB / KT;
    static_assert(KB % KT == 0, "");
    __shared__ __align__(16) float xs[2][KT * BT];   // [k][b], 4 KB/buf
    __shared__ __align__(16) float ws[2][KT * OT];   // [k][o], 8 KB/buf

    const int tid  = threadIdx.x;        // 0..127
    const int to   = tid & 15;           // o-quad selector (0..15)
    const int tb   = tid >> 4;           // b-quad selector (0..7)
    const int wave = tid >> 6;           // 0..1
    const int lane = tid & 63;
    const int o0 = blockIdx.x * OT;
    const int b0 = blockIdx.y * BT;
    const int kz = blockIdx.z;
    const int kbase = kz * KB;

    float acc[8][8];                     // SCALAR regs — verified codegen
    #pragma unroll
    for (int i = 0; i < 8; ++i)
        #pragma unroll
        for (int j = 0; j < 8; ++j)
            acc[i][j] = -FLT_MAX;

    // stage chunk c: x tile = KT*64 floats = 4 x 1KB DMA (4 k-rows each);
    //               w tile = KT*128 floats = 8 x 1KB DMA (2 k-rows each)
    const int xr4 = lane >> 4;           // k-subrow within x DMA (4 rows of 64)
    const int xcb = (lane & 15) * 4;
    const int wr2 = lane >> 5;           // k-subrow within w DMA (2 rows of 128)
    const int wcb = (lane & 31) * 4;

    auto stage = [&](int c, int buf) {
        const int k0 = kbase + c * KT;
        #pragma unroll
        for (int i = 0; i < 2; ++i) {
            const int t = wave * 2 + i;                    // 0..3, wave-uniform
            g2lds16(&xT[(size_t)(k0 + 4 * t + xr4) * B_DIM + b0 + xcb],
                    &xs[buf][t * 256]);
        }
        #pragma unroll
        for (int i = 0; i < 4; ++i) {
            const int t = wave * 4 + i;                    // 0..7, wave-uniform
            g2lds16(&wT[(size_t)(k0 + 2 * t + wr2) * O_DIM + o0 + wcb],
                    &ws[buf][t * 256]);
        }
    };

    auto compute = [&](int buf) {
        const float* xB = &xs[buf][4 * tb];   // all reads: static imm offsets
        const float* wB = &ws[buf][4 * to];
        #pragma unroll                         // FULL unroll: 8 k-pairs
        for (int k = 0; k < KT; k += 2) {
            const float4 xa0 = *(const float4*)&xB[k * BT];
            const float4 xa1 = *(const float4*)&xB[k * BT + 32];
            const float4 xb0 = *(const float4*)&xB[(k + 1) * BT];
            const float4 xb1 = *(const float4*)&xB[(k + 1) * BT + 32];
            const float4 wa0 = *(const float4*)&wB[k * OT];
            const float4 wa1 = *(const float4*)&wB[k * OT + 64];
            const float4 wb0 = *(const float4*)&wB[(k + 1) * OT];
            const float4 wb1 = *(const float4*)&wB[(k + 1) * OT + 64];

            const float xa[8] = {xa0.x, xa0.y, xa0.z, xa0.w, xa1.x, xa1.y, xa1.z, xa1.w};
            const float xb[8] = {xb0.x, xb0.y, xb0.z, xb0.w, xb1.x, xb1.y, xb1.z, xb1.w};
            // named f32x2 aliases of consecutive regs out of the b128 loads
            const f32x2 wa00 = {wa0.x, wa0.y}, wa01 = {wa0.z, wa0.w};
            const f32x2 wa10 = {wa1.x, wa1.y}, wa11 = {wa1.z, wa1.w};
            const f32x2 wb00 = {wb0.x, wb0.y}, wb01 = {wb0.z, wb0.w};
            const f32x2 wb10 = {wb1.x, wb1.y}, wb11 = {wb1.z, wb1.w};

            #pragma unroll
            for (int i = 0; i < 8; ++i) {
                const f32x2 xpa = {xa[i], xa[i]};   // splat (op_sel)
                const f32x2 xpb = {xb[i], xb[i]};
                {
                    const f32x2 s0 = wa00 + xpa;    // v_pk_add_f32
                    const f32x2 s1 = wb00 + xpb;    // v_pk_add_f32
                    acc[i][0] = fmaxf(acc[i][0], fmaxf(s0.x, s1.x));  // v_max3
                    acc[i][1] = fmaxf(acc[i][1], fmaxf(s0.y, s1.y));
                }
                {
                    const f32x2 s0 = wa01 + xpa;
                    const f32x2 s1 = wb01 + xpb;
                    acc[i][2] = fmaxf(acc[i][2], fmaxf(s0.x, s1.x));
                    acc[i][3] = fmaxf(acc[i][3], fmaxf(s0.y, s1.y));
                }
                {
                    const f32x2 s0 = wa10 + xpa;
                    const f32x2 s1 = wb10 + xpb;
                    acc[i][4] = fmaxf(acc[i][4], fmaxf(s0.x, s1.x));
                    acc[i][5] = fmaxf(acc[i][5], fmaxf(s0.y, s1.y));
                }
                {
                    const f32x2 s0 = wa11 + xpa;
                    const f32x2 s1 = wb11 + xpb;
                    acc[i][6] = fmaxf(acc[i][6], fmaxf(s0.x, s1.x));
                    acc[i][7] = fmaxf(acc[i][7], fmaxf(s0.y, s1.y));
                }
            }
        }
    };

    stage(0, 0);
    #pragma unroll
    for (int c = 0; c < NCH; ++c) {
        __syncthreads();                              // chunk c staged; prev reads done
        if (c + 1 < NCH) stage(c + 1, (c + 1) & 1);   // DMA overlaps compute
        compute(c & 1);
    }

    // epilogue: coalesced float4 stores into private slab
    float* pout = part + (size_t)kz * (B_DIM * O_DIM);
    #pragma unroll
    for (int i = 0; i < 8; ++i) {
        const int b = b0 + (i >> 2) * 32 + 4 * tb + (i & 3);
        float4 v0 = make_float4(acc[i][0], acc[i][1], acc[i][2], acc[i][3]);
        float4 v1 = make_float4(acc[i][4], acc[i][5], acc[i][6], acc[i][7]);
        *(float4*)&pout[(size_t)b * O_DIM + o0 + 4 * to]      = v0;
        *(float4*)&pout[(size_t)b * O_DIM + o0 + 64 + 4 * to] = v1;
    }
}

// ---- fused transpose: z=0 -> xT from x (512x1024); z=1,2 -> wT halves
__global__ __launch_bounds__(256) void transpose3(
    const float* __restrict__ x, float* __restrict__ xT,
    const float* __restrict__ W, float* __restrict__ wT)
{
    __shared__ float tile[32][33];
    const int tx = threadIdx.x;   // 0..31
    const int ty = threadIdx.y;   // 0..7
    const int z  = blockIdx.z;
    const float* in; float* out; int dst_ld;
    if (z == 0) { in = x;                  out = xT;            dst_ld = B_DIM; }
    else        { in = W + (z - 1) * 512 * I_DIM;
                  out = wT + (z - 1) * 512;                     dst_ld = O_DIM; }
    const int r0 = blockIdx.y * 32;
    const int c0 = blockIdx.x * 32;
    #pragma unroll
    for (int i = 0; i < 4; ++i)
        tile[ty + 8 * i][tx] = in[(size_t)(r0 + ty + 8 * i) * I_DIM + c0 + tx];
    __syncthreads();
    #pragma unroll
    for (int i = 0; i < 4; ++i)
        out[(size_t)(c0 + ty + 8 * i) * dst_ld + r0 + tx] = tile[tx][ty + 8 * i];
}

template <int KS>
__global__ __launch_bounds__(256) void trop_reduce(
    const float* __restrict__ part, float* __restrict__ y)
{
    constexpr int N4 = B_DIM * O_DIM / 4;
    const int idx = blockIdx.x * 256 + threadIdx.x;
    const float4* p = (const float4*)part;
    float4 m = p[idx];
    #pragma unroll
    for (int s = 1; s < KS; ++s) {
        const float4 v = p[(size_t)s * N4 + idx];
        m.x = fmaxf(m.x, v.x); m.y = fmaxf(m.y, v.y);
        m.z = fmaxf(m.z, v.z); m.w = fmaxf(m.w, v.w);
    }
    ((float4*)y)[idx] = m;
}

// correctness-net fallback if d_ws is tiny
__global__ __launch_bounds__(256) void trop_naive(
    const float* __restrict__ x, const float* __restrict__ W,
    float* __restrict__ y)
{
    const int idx = blockIdx.x * 256 + threadIdx.x;
    const int b = idx / O_DIM, o = idx % O_DIM;
    float m = -FLT_MAX;
    for (int i = 0; i < I_DIM; ++i)
        m = fmaxf(m, x[b * I_DIM + i] + W[o * I_DIM + i]);
    y[idx] = m;
}

extern "C" void kernel_launch(void* const* d_in, const int* in_sizes, int n_in,
                              void* d_out, int out_size, void* d_ws, size_t ws_size,
                              hipStream_t stream) {
    const float* x = (const float*)d_in[0];
    const float* W = (const float*)d_in[1];
    float* y = (float*)d_out;

    const size_t slab  = (size_t)B_DIM * O_DIM * sizeof(float);   // 2 MB
    const size_t xT_sz = (size_t)B_DIM * I_DIM * sizeof(float);   // 2 MB
    const size_t wT_sz = (size_t)O_DIM * I_DIM * sizeof(float);   // 4 MB
    const dim3 rgrid(B_DIM * O_DIM / 4 / 256);
    const dim3 tgrid(I_DIM / 32, 512 / 32, 3);
    const dim3 tblk(32, 8);

    if (ws_size >= 16 * slab + xT_sz + wT_sz) {          // 38 MB
        float* part = (float*)d_ws;
        float* xT = part + 16 * (B_DIM * O_DIM);
        float* wT = xT + B_DIM * I_DIM;
        transpose3<<<tgrid, tblk, 0, stream>>>(x, xT, W, wT);
        trop_main<I_DIM / 16><<<dim3(O_DIM / OT, B_DIM / BT, 16), 128, 0, stream>>>(xT, wT, part);
        trop_reduce<16><<<rgrid, 256, 0, stream>>>(part, y);
    } else if (ws_size >= 8 * slab + xT_sz + wT_sz) {    // 22 MB
        float* part = (float*)d_ws;
        float* xT = part + 8 * (B_DIM * O_DIM);
        float* wT = xT + B_DIM * I_DIM;
        transpose3<<<tgrid, tblk, 0, stream>>>(x, xT, W, wT);
        trop_main<I_DIM / 8><<<dim3(O_DIM / OT, B_DIM / BT, 8), 128, 0, stream>>>(xT, wT, part);
        trop_reduce<8><<<rgrid, 256, 0, stream>>>(part, y);
    } else if (ws_size >= xT_sz + wT_sz) {               // 6 MB: no K-split
        float* xT = (float*)d_ws;
        float* wT = xT + B_DIM * I_DIM;
        transpose3<<<tgrid, tblk, 0, stream>>>(x, xT, W, wT);
        trop_main<I_DIM><<<dim3(O_DIM / OT, B_DIM / BT, 1), 128, 0, stream>>>(xT, wT, y);
    } else {
        trop_naive<<<dim3(B_DIM * O_DIM / 256), 256, 0, stream>>>(x, W, y);
    }
}

// Round 10
// 106.644 us; speedup vs baseline: 6.8430x; 6.8430x over previous
//
#include <hip/hip_runtime.h>
#include <float.h>

// Tropical (max-plus) linear: y[b,o] = max_i (x[b,i] + W[o,i])
// B=512, I=1024, O=1024, fp32. No MFMA (max-plus semiring) -> fp32 VALU.
//
// Round-10 = round-8 kernel body VERBATIM; only the launch shape changes.
//  ABSOLUTE RULE (r5/r7/r9 all detonated ~8x on allocator demotion->scratch):
//   no ext_vector/floatN types anywhere in inner-loop dataflow. float4 only
//   as an immediate LDS-load temp instantly decomposed into scalar float[8].
//  Occupancy ledger: waves/SIMD = blocks/CU x waves/block / 4. All prior
//   rounds ran 2 waves/SIMD. This round: KSPLIT=32 -> 1024 blocks of 256 thr
//   = 4 blocks/CU = 16 waves/CU = 4 waves/SIMD (VGPR 128 x 16 waves = 512/lane
//   exactly; LDS 32 KB x 4 = 128 <= 160 KB). Tests the exposed-latency theory:
//   cross-block overlap of barrier drains / DMA prologues.
//  Cost accepted: slabs 32->64 MB (+~5 us stores, +~5 us reduce).

#define B_DIM 512
#define I_DIM 1024
#define O_DIM 1024
#define BT 128
#define OT 128
#define KT 16            // k per staged chunk (8 KB per tile per buffer)

__device__ __forceinline__ void g2lds16(const float* g, float* l) {
    __builtin_amdgcn_global_load_lds(
        (const __attribute__((address_space(1))) void*)g,
        (__attribute__((address_space(3))) void*)l, 16, 0, 0);
}

template <int KB>   // k handled per block
__global__ __launch_bounds__(256, 2) void trop_main(
    const float* __restrict__ xT,   // [I_DIM][B_DIM]
    const float* __restrict__ wT,   // [I_DIM][O_DIM]
    float* __restrict__ part)       // [KSPLIT][B_DIM][O_DIM] (or y if z==1)
{
    constexpr int NCH = KB / KT;
    static_assert(KB % KT == 0, "");
    __shared__ __align__(16) float xs[2][KT * BT];   // [k][b], 8 KB/buf
    __shared__ __align__(16) float ws[2][KT * OT];   // [k][o], 8 KB/buf

    const int tid  = threadIdx.x;
    const int to   = tid & 15;      // o-quad selector
    const int tb   = tid >> 4;      // b-quad selector
    const int wave = tid >> 6;
    const int lane = tid & 63;
    const int o0 = blockIdx.x * OT;
    const int b0 = blockIdx.y * BT;
    const int kz = blockIdx.z;
    const int kbase = kz * KB;

    const int rk = lane >> 5;           // k-subrow within one 1KB DMA
    const int cb = (lane & 31) * 4;     // col offset (lane*16B)

    float acc[8][8];                    // SCALAR regs — verified codegen
    #pragma unroll
    for (int i = 0; i < 8; ++i)
        #pragma unroll
        for (int j = 0; j < 8; ++j)
            acc[i][j] = -FLT_MAX;

    // chunk = 16 k-rows: 8 x 1KB DMAs per tile (2 k-rows each); 2 per wave
    auto stage = [&](int c, int buf) {
        const int k0 = kbase + c * KT;
        #pragma unroll
        for (int i = 0; i < 2; ++i) {
            const int t = wave * 2 + i;                 // 0..7, wave-uniform
            g2lds16(&xT[(size_t)(k0 + 2 * t + rk) * B_DIM + b0 + cb],
                    &xs[buf][t * 256]);
        }
        #pragma unroll
        for (int i = 0; i < 2; ++i) {
            const int t = wave * 2 + i;
            g2lds16(&wT[(size_t)(k0 + 2 * t + rk) * O_DIM + o0 + cb],
                    &ws[buf][t * 256]);
        }
    };

    auto compute = [&](int buf) {
        const float* xB = &xs[buf][4 * tb];   // all reads: static imm offsets
        const float* wB = &ws[buf][4 * to];
        #pragma unroll                         // FULL unroll: 8 k-pairs
        for (int k = 0; k < KT; k += 2) {
            const float4 xa0 = *(const float4*)&xB[k * BT];
            const float4 xa1 = *(const float4*)&xB[k * BT + 64];
            const float4 xb0 = *(const float4*)&xB[(k + 1) * BT];
            const float4 xb1 = *(const float4*)&xB[(k + 1) * BT + 64];
            const float4 wa0 = *(const float4*)&wB[k * OT];
            const float4 wa1 = *(const float4*)&wB[k * OT + 64];
            const float4 wb0 = *(const float4*)&wB[(k + 1) * OT];
            const float4 wb1 = *(const float4*)&wB[(k + 1) * OT + 64];

            const float xa[8] = {xa0.x, xa0.y, xa0.z, xa0.w, xa1.x, xa1.y, xa1.z, xa1.w};
            const float xb[8] = {xb0.x, xb0.y, xb0.z, xb0.w, xb1.x, xb1.y, xb1.z, xb1.w};
            const float wa[8] = {wa0.x, wa0.y, wa0.z, wa0.w, wa1.x, wa1.y, wa1.z, wa1.w};
            const float wb[8] = {wb0.x, wb0.y, wb0.z, wb0.w, wb1.x, wb1.y, wb1.z, wb1.w};

            #pragma unroll
            for (int i = 0; i < 8; ++i)
                #pragma unroll
                for (int j = 0; j < 8; ++j) {
                    const float s0 = xa[i] + wa[j];
                    const float s1 = xb[i] + wb[j];
                    acc[i][j] = fmaxf(acc[i][j], fmaxf(s0, s1));   // v_max3_f32
                }
        }
    };

    stage(0, 0);
    #pragma unroll
    for (int c = 0; c < NCH; ++c) {
        __syncthreads();                              // chunk c staged; prev reads done
        if (c + 1 < NCH) stage(c + 1, (c + 1) & 1);   // DMA overlaps compute
        compute(c & 1);
    }

    // epilogue: coalesced float4 stores into private slab
    float* pout = part + (size_t)kz * (B_DIM * O_DIM);
    #pragma unroll
    for (int i = 0; i < 8; ++i) {
        const int b = b0 + (i >> 2) * 64 + 4 * tb + (i & 3);
        float4 v0 = make_float4(acc[i][0], acc[i][1], acc[i][2], acc[i][3]);
        float4 v1 = make_float4(acc[i][4], acc[i][5], acc[i][6], acc[i][7]);
        *(float4*)&pout[(size_t)b * O_DIM + o0 + 4 * to]      = v0;
        *(float4*)&pout[(size_t)b * O_DIM + o0 + 64 + 4 * to] = v1;
    }
}

// ---- fused transpose: z=0 -> xT from x (512x1024); z=1,2 -> wT halves
__global__ __launch_bounds__(256) void transpose3(
    const float* __restrict__ x, float* __restrict__ xT,
    const float* __restrict__ W, float* __restrict__ wT)
{
    __shared__ float tile[32][33];
    const int tx = threadIdx.x;   // 0..31
    const int ty = threadIdx.y;   // 0..7
    const int z  = blockIdx.z;
    const float* in; float* out; int dst_ld;
    if (z == 0) { in = x;                  out = xT;            dst_ld = B_DIM; }
    else        { in = W + (z - 1) * 512 * I_DIM;
                  out = wT + (z - 1) * 512;                     dst_ld = O_DIM; }
    const int r0 = blockIdx.y * 32;
    const int c0 = blockIdx.x * 32;
    #pragma unroll
    for (int i = 0; i < 4; ++i)
        tile[ty + 8 * i][tx] = in[(size_t)(r0 + ty + 8 * i) * I_DIM + c0 + tx];
    __syncthreads();
    #pragma unroll
    for (int i = 0; i < 4; ++i)
        out[(size_t)(c0 + ty + 8 * i) * dst_ld + r0 + tx] = tile[tx][ty + 8 * i];
}

template <int KS>
__global__ __launch_bounds__(256) void trop_reduce(
    const float* __restrict__ part, float* __restrict__ y)
{
    constexpr int N4 = B_DIM * O_DIM / 4;
    const int idx = blockIdx.x * 256 + threadIdx.x;
    const float4* p = (const float4*)part;
    float4 m = p[idx];
    #pragma unroll
    for (int s = 1; s < KS; ++s) {
        const float4 v = p[(size_t)s * N4 + idx];
        m.x = fmaxf(m.x, v.x); m.y = fmaxf(m.y, v.y);
        m.z = fmaxf(m.z, v.z); m.w = fmaxf(m.w, v.w);
    }
    ((float4*)y)[idx] = m;
}

// correctness-net fallback if d_ws is tiny
__global__ __launch_bounds__(256) void trop_naive(
    const float* __restrict__ x, const float* __restrict__ W,
    float* __restrict__ y)
{
    const int idx = blockIdx.x * 256 + threadIdx.x;
    const int b = idx / O_DIM, o = idx % O_DIM;
    float m = -FLT_MAX;
    for (int i = 0; i < I_DIM; ++i)
        m = fmaxf(m, x[b * I_DIM + i] + W[o * I_DIM + i]);
    y[idx] = m;
}

extern "C" void kernel_launch(void* const* d_in, const int* in_sizes, int n_in,
                              void* d_out, int out_size, void* d_ws, size_t ws_size,
                              hipStream_t stream) {
    const float* x = (const float*)d_in[0];
    const float* W = (const float*)d_in[1];
    float* y = (float*)d_out;

    const size_t slab  = (size_t)B_DIM * O_DIM * sizeof(float);   // 2 MB
    const size_t xT_sz = (size_t)B_DIM * I_DIM * sizeof(float);   // 2 MB
    const size_t wT_sz = (size_t)O_DIM * I_DIM * sizeof(float);   // 4 MB
    const dim3 rgrid(B_DIM * O_DIM / 4 / 256);
    const dim3 tgrid(I_DIM / 32, 512 / 32, 3);
    const dim3 tblk(32, 8);

    if (ws_size >= 32 * slab + xT_sz + wT_sz) {          // 70 MB: 4 blocks/CU
        float* part = (float*)d_ws;
        float* xT = part + 32 * (size_t)(B_DIM * O_DIM);
        float* wT = xT + B_DIM * I_DIM;
        transpose3<<<tgrid, tblk, 0, stream>>>(x, xT, W, wT);
        trop_main<I_DIM / 32><<<dim3(O_DIM / OT, B_DIM / BT, 32), 256, 0, stream>>>(xT, wT, part);
        trop_reduce<32><<<rgrid, 256, 0, stream>>>(part, y);
    } else if (ws_size >= 16 * slab + xT_sz + wT_sz) {   // 38 MB: r8 config
        float* part = (float*)d_ws;
        float* xT = part + 16 * (size_t)(B_DIM * O_DIM);
        float* wT = xT + B_DIM * I_DIM;
        transpose3<<<tgrid, tblk, 0, stream>>>(x, xT, W, wT);
        trop_main<I_DIM / 16><<<dim3(O_DIM / OT, B_DIM / BT, 16), 256, 0, stream>>>(xT, wT, part);
        trop_reduce<16><<<rgrid, 256, 0, stream>>>(part, y);
    } else if (ws_size >= 8 * slab + xT_sz + wT_sz) {    // 22 MB
        float* part = (float*)d_ws;
        float* xT = part + 8 * (size_t)(B_DIM * O_DIM);
        float* wT = xT + B_DIM * I_DIM;
        transpose3<<<tgrid, tblk, 0, stream>>>(x, xT, W, wT);
        trop_main<I_DIM / 8><<<dim3(O_DIM / OT, B_DIM / BT, 8), 256, 0, stream>>>(xT, wT, part);
        trop_reduce<8><<<rgrid, 256, 0, stream>>>(part, y);
    } else if (ws_size >= xT_sz + wT_sz) {               // 6 MB: no K-split
        float* xT = (float*)d_ws;
        float* wT = xT + B_DIM * I_DIM;
        transpose3<<<tgrid, tblk, 0, stream>>>(x, xT, W, wT);
        trop_main<I_DIM><<<dim3(O_DIM / OT, B_DIM / BT, 1), 256, 0, stream>>>(xT, wT, y);
    } else {
        trop_naive<<<dim3(B_DIM * O_DIM / 256), 256, 0, stream>>>(x, W, y);
    }
}

// Round 11
// 89.194 us; speedup vs baseline: 8.1817x; 1.1956x over previous
//
#include <hip/hip_runtime.h>
#include <float.h>

// Tropical (max-plus) linear: y[b,o] = max_i (x[b,i] + W[o,i])
// B=512, I=1024, O=1024, fp32. No MFMA (max-plus semiring) -> fp32 VALU.
//
// Round-11 = r8's scalar body VERBATIM + r9's block geometry (clean re-test;
// r9's original run was invalidated by f32x2 register demotion).
//  ABSOLUTE RULE (r5/r7/r9 demotion detonations): no ext_vector/floatN types
//  in inner-loop dataflow. float4 only as an immediate LDS-load temp
//  instantly decomposed into scalar float[8]; all register state scalar.
//  Single variable vs r8: block shape 128x128/256thr -> 64x128/128thr.
//   - KSPLIT=16, NCH=4, slab bytes, reduce cost: ALL unchanged from r8.
//   - 1024 blocks = 4 blocks/CU (LDS 24 KB/blk, 96 KB/CU), still 2 waves/SIMD,
//     but 4 independent barrier domains per CU vs r8's 2 -> one block's
//     barrier drain overlaps another's compute.
//  r10 lesson: occupancy alone (4 waves/SIMD, NCH=2) regressed main 35->41.5
//  with VALUBusy only 52% -- per-block fixed costs and epilogue bytes matter
//  as much as wave count. This round holds those constant.

#define B_DIM 512
#define I_DIM 1024
#define O_DIM 1024
#define BT 64            // b-tile per block
#define OT 128           // o-tile per block
#define KT 16            // k per staged chunk

__device__ __forceinline__ void g2lds16(const float* g, float* l) {
    __builtin_amdgcn_global_load_lds(
        (const __attribute__((address_space(1))) void*)g,
        (__attribute__((address_space(3))) void*)l, 16, 0, 0);
}

template <int KB>   // k handled per block
__global__ __launch_bounds__(128, 2) void trop_main(
    const float* __restrict__ xT,   // [I_DIM][B_DIM]
    const float* __restrict__ wT,   // [I_DIM][O_DIM]
    float* __restrict__ part)       // [KSPLIT][B_DIM][O_DIM] (or y if z==1)
{
    constexpr int NCH = KB / KT;
    static_assert(KB % KT == 0, "");
    __shared__ __align__(16) float xs[2][KT * BT];   // [k][b], 4 KB/buf
    __shared__ __align__(16) float ws[2][KT * OT];   // [k][o], 8 KB/buf

    const int tid  = threadIdx.x;        // 0..127
    const int to   = tid & 15;           // o-quad selector (0..15)
    const int tb   = tid >> 4;           // b-quad selector (0..7)
    const int wave = tid >> 6;           // 0..1
    const int lane = tid & 63;
    const int o0 = blockIdx.x * OT;
    const int b0 = blockIdx.y * BT;
    const int kz = blockIdx.z;
    const int kbase = kz * KB;

    float acc[8][8];                     // SCALAR regs — verified codegen
    #pragma unroll
    for (int i = 0; i < 8; ++i)
        #pragma unroll
        for (int j = 0; j < 8; ++j)
            acc[i][j] = -FLT_MAX;

    // stage chunk c (r9-verified lane geometry):
    //  x tile = KT*64 floats = 4 x 1KB DMA (4 k-rows of 64 each), 2 per wave
    //  w tile = KT*128 floats = 8 x 1KB DMA (2 k-rows of 128 each), 4 per wave
    const int xr4 = lane >> 4;           // k-subrow within x DMA
    const int xcb = (lane & 15) * 4;
    const int wr2 = lane >> 5;           // k-subrow within w DMA
    const int wcb = (lane & 31) * 4;

    auto stage = [&](int c, int buf) {
        const int k0 = kbase + c * KT;
        #pragma unroll
        for (int i = 0; i < 2; ++i) {
            const int t = wave * 2 + i;                    // 0..3, wave-uniform
            g2lds16(&xT[(size_t)(k0 + 4 * t + xr4) * B_DIM + b0 + xcb],
                    &xs[buf][t * 256]);
        }
        #pragma unroll
        for (int i = 0; i < 4; ++i) {
            const int t = wave * 4 + i;                    // 0..7, wave-uniform
            g2lds16(&wT[(size_t)(k0 + 2 * t + wr2) * O_DIM + o0 + wcb],
                    &ws[buf][t * 256]);
        }
    };

    auto compute = [&](int buf) {
        const float* xB = &xs[buf][4 * tb];   // all reads: static imm offsets
        const float* wB = &ws[buf][4 * to];
        #pragma unroll                         // FULL unroll: 8 k-pairs
        for (int k = 0; k < KT; k += 2) {
            const float4 xa0 = *(const float4*)&xB[k * BT];
            const float4 xa1 = *(const float4*)&xB[k * BT + 32];
            const float4 xb0 = *(const float4*)&xB[(k + 1) * BT];
            const float4 xb1 = *(const float4*)&xB[(k + 1) * BT + 32];
            const float4 wa0 = *(const float4*)&wB[k * OT];
            const float4 wa1 = *(const float4*)&wB[k * OT + 64];
            const float4 wb0 = *(const float4*)&wB[(k + 1) * OT];
            const float4 wb1 = *(const float4*)&wB[(k + 1) * OT + 64];

            const float xa[8] = {xa0.x, xa0.y, xa0.z, xa0.w, xa1.x, xa1.y, xa1.z, xa1.w};
            const float xb[8] = {xb0.x, xb0.y, xb0.z, xb0.w, xb1.x, xb1.y, xb1.z, xb1.w};
            const float wa[8] = {wa0.x, wa0.y, wa0.z, wa0.w, wa1.x, wa1.y, wa1.z, wa1.w};
            const float wb[8] = {wb0.x, wb0.y, wb0.z, wb0.w, wb1.x, wb1.y, wb1.z, wb1.w};

            #pragma unroll
            for (int i = 0; i < 8; ++i)
                #pragma unroll
                for (int j = 0; j < 8; ++j) {
                    const float s0 = xa[i] + wa[j];
                    const float s1 = xb[i] + wb[j];
                    acc[i][j] = fmaxf(acc[i][j], fmaxf(s0, s1));   // v_max3_f32
                }
        }
    };

    stage(0, 0);
    #pragma unroll
    for (int c = 0; c < NCH; ++c) {
        __syncthreads();                              // chunk c staged; prev reads done
        if (c + 1 < NCH) stage(c + 1, (c + 1) & 1);   // DMA overlaps compute
        compute(c & 1);
    }

    // epilogue: coalesced float4 stores into private slab
    float* pout = part + (size_t)kz * (B_DIM * O_DIM);
    #pragma unroll
    for (int i = 0; i < 8; ++i) {
        const int b = b0 + (i >> 2) * 32 + 4 * tb + (i & 3);
        float4 v0 = make_float4(acc[i][0], acc[i][1], acc[i][2], acc[i][3]);
        float4 v1 = make_float4(acc[i][4], acc[i][5], acc[i][6], acc[i][7]);
        *(float4*)&pout[(size_t)b * O_DIM + o0 + 4 * to]      = v0;
        *(float4*)&pout[(size_t)b * O_DIM + o0 + 64 + 4 * to] = v1;
    }
}

// ---- fused transpose: z=0 -> xT from x (512x1024); z=1,2 -> wT halves
__global__ __launch_bounds__(256) void transpose3(
    const float* __restrict__ x, float* __restrict__ xT,
    const float* __restrict__ W, float* __restrict__ wT)
{
    __shared__ float tile[32][33];
    const int tx = threadIdx.x;   // 0..31
    const int ty = threadIdx.y;   // 0..7
    const int z  = blockIdx.z;
    const float* in; float* out; int dst_ld;
    if (z == 0) { in = x;                  out = xT;            dst_ld = B_DIM; }
    else        { in = W + (z - 1) * 512 * I_DIM;
                  out = wT + (z - 1) * 512;                     dst_ld = O_DIM; }
    const int r0 = blockIdx.y * 32;
    const int c0 = blockIdx.x * 32;
    #pragma unroll
    for (int i = 0; i < 4; ++i)
        tile[ty + 8 * i][tx] = in[(size_t)(r0 + ty + 8 * i) * I_DIM + c0 + tx];
    __syncthreads();
    #pragma unroll
    for (int i = 0; i < 4; ++i)
        out[(size_t)(c0 + ty + 8 * i) * dst_ld + r0 + tx] = tile[tx][ty + 8 * i];
}

template <int KS>
__global__ __launch_bounds__(256) void trop_reduce(
    const float* __restrict__ part, float* __restrict__ y)
{
    constexpr int N4 = B_DIM * O_DIM / 4;
    const int idx = blockIdx.x * 256 + threadIdx.x;
    const float4* p = (const float4*)part;
    float4 m = p[idx];
    #pragma unroll
    for (int s = 1; s < KS; ++s) {
        const float4 v = p[(size_t)s * N4 + idx];
        m.x = fmaxf(m.x, v.x); m.y = fmaxf(m.y, v.y);
        m.z = fmaxf(m.z, v.z); m.w = fmaxf(m.w, v.w);
    }
    ((float4*)y)[idx] = m;
}

// correctness-net fallback if d_ws is tiny
__global__ __launch_bounds__(256) void trop_naive(
    const float* __restrict__ x, const float* __restrict__ W,
    float* __restrict__ y)
{
    const int idx = blockIdx.x * 256 + threadIdx.x;
    const int b = idx / O_DIM, o = idx % O_DIM;
    float m = -FLT_MAX;
    for (int i = 0; i < I_DIM; ++i)
        m = fmaxf(m, x[b * I_DIM + i] + W[o * I_DIM + i]);
    y[idx] = m;
}

extern "C" void kernel_launch(void* const* d_in, const int* in_sizes, int n_in,
                              void* d_out, int out_size, void* d_ws, size_t ws_size,
                              hipStream_t stream) {
    const float* x = (const float*)d_in[0];
    const float* W = (const float*)d_in[1];
    float* y = (float*)d_out;

    const size_t slab  = (size_t)B_DIM * O_DIM * sizeof(float);   // 2 MB
    const size_t xT_sz = (size_t)B_DIM * I_DIM * sizeof(float);   // 2 MB
    const size_t wT_sz = (size_t)O_DIM * I_DIM * sizeof(float);   // 4 MB
    const dim3 rgrid(B_DIM * O_DIM / 4 / 256);
    const dim3 tgrid(I_DIM / 32, 512 / 32, 3);
    const dim3 tblk(32, 8);

    if (ws_size >= 16 * slab + xT_sz + wT_sz) {          // 38 MB: 4 blocks/CU
        float* part = (float*)d_ws;
        float* xT = part + 16 * (size_t)(B_DIM * O_DIM);
        float* wT = xT + B_DIM * I_DIM;
        transpose3<<<tgrid, tblk, 0, stream>>>(x, xT, W, wT);
        trop_main<I_DIM / 16><<<dim3(O_DIM / OT, B_DIM / BT, 16), 128, 0, stream>>>(xT, wT, part);
        trop_reduce<16><<<rgrid, 256, 0, stream>>>(part, y);
    } else if (ws_size >= 8 * slab + xT_sz + wT_sz) {    // 22 MB
        float* part = (float*)d_ws;
        float* xT = part + 8 * (size_t)(B_DIM * O_DIM);
        float* wT = xT + B_DIM * I_DIM;
        transpose3<<<tgrid, tblk, 0, stream>>>(x, xT, W, wT);
        trop_main<I_DIM / 8><<<dim3(O_DIM / OT, B_DIM / BT, 8), 128, 0, stream>>>(xT, wT, part);
        trop_reduce<8><<<rgrid, 256, 0, stream>>>(part, y);
    } else if (ws_size >= xT_sz + wT_sz) {               // 6 MB: no K-split
        float* xT = (float*)d_ws;
        float* wT = xT + B_DIM * I_DIM;
        transpose3<<<tgrid, tblk, 0, stream>>>(x, xT, W, wT);
        trop_main<I_DIM><<<dim3(O_DIM / OT, B_DIM / BT, 1), 128, 0, stream>>>(xT, wT, y);
    } else {
        trop_naive<<<dim3(B_DIM * O_DIM / 256), 256, 0, stream>>>(x, W, y);
    }
}